// Round 2
// baseline (2156.137 us; speedup 1.0000x reference)
//
#include <hip/hip_runtime.h>
#include <stdint.h>

#define B_ 8
#define L_ 2048
#define D_ 1024
#define H_ 4
#define DK_ 256
#define MM_ (B_*L_)   // 16384
#define KK_ D_        // 1024
#define NN_ D_        // 1024

typedef __bf16 bf16x8 __attribute__((ext_vector_type(8)));
typedef float  f32x4  __attribute__((ext_vector_type(4)));

__device__ __forceinline__ uint32_t f2bf_u(float f) {
  union { float f; uint32_t u; } v; v.f = f;
  return (v.u + 0x7FFFu + ((v.u >> 16) & 1u)) >> 16;
}
__device__ __forceinline__ uint32_t pack2(float x, float y) {
  return f2bf_u(x) | (f2bf_u(y) << 16);
}

// -------- fp32 -> bf16 convert (fast path only) --------
__global__ __launch_bounds__(256) void cvt_kernel(const float* __restrict__ src,
                                                  unsigned short* __restrict__ dst, int n4) {
  int i = blockIdx.x * blockDim.x + threadIdx.x;
  int stride = gridDim.x * blockDim.x;
  for (; i < n4; i += stride) {
    float4 f = ((const float4*)src)[i];
    uint2 u; u.x = pack2(f.x, f.y); u.y = pack2(f.z, f.w);
    ((uint2*)dst)[i] = u;
  }
}

// -------- GEMM: out[m,n] = sum_k A[m,k]*W[n,k] + bias[n] --------
// ABF/WBF: operand is bf16 (1) or fp32 (0).  EPI: 0=bf16 row-major, 1=bf16 transposed vt, 2=fp32
template<int ABF, int WBF, int EPI>
__global__ __launch_bounds__(256)
void gemm_kernel(const void* __restrict__ Ap, const void* __restrict__ Wp,
                 const float* __restrict__ bias, void* __restrict__ outp)
{
  __shared__ short smem[18432];          // A: [128][72], B: [128][72]; reused for transpose
  short* As = smem;
  short* Bs = smem + 9216;

  const int tid  = threadIdx.x;
  const int lane = tid & 63;
  const int wave = tid >> 6;
  const int quad = lane >> 4;
  const int l16  = lane & 15;
  const int wm = (wave >> 1) * 64;
  const int wn = (wave & 1) * 64;
  const int m0 = blockIdx.y * 128;
  const int n0 = blockIdx.x * 128;

  const int srow = tid >> 1;             // 0..127
  const int scol = (tid & 1) * 32;       // 0 or 32

  f32x4 acc[4][4] = {};

  for (int ks = 0; ks < KK_ / 64; ks++) {
    const int k0 = ks * 64;
    {
      short* dst = &As[srow * 72 + scol];
      if constexpr (ABF) {
        const uint4* src = (const uint4*)((const unsigned short*)Ap + (size_t)(m0 + srow) * KK_ + k0 + scol);
        #pragma unroll
        for (int i = 0; i < 4; i++) ((uint4*)dst)[i] = src[i];
      } else {
        const float4* src = (const float4*)((const float*)Ap + (size_t)(m0 + srow) * KK_ + k0 + scol);
        #pragma unroll
        for (int i = 0; i < 4; i++) {
          float4 a = src[2*i], b2 = src[2*i+1];
          uint4 p;
          p.x = pack2(a.x, a.y);  p.y = pack2(a.z, a.w);
          p.z = pack2(b2.x, b2.y); p.w = pack2(b2.z, b2.w);
          ((uint4*)dst)[i] = p;
        }
      }
      short* dstb = &Bs[srow * 72 + scol];
      if constexpr (WBF) {
        const uint4* src = (const uint4*)((const unsigned short*)Wp + (size_t)(n0 + srow) * KK_ + k0 + scol);
        #pragma unroll
        for (int i = 0; i < 4; i++) ((uint4*)dstb)[i] = src[i];
      } else {
        const float4* src = (const float4*)((const float*)Wp + (size_t)(n0 + srow) * KK_ + k0 + scol);
        #pragma unroll
        for (int i = 0; i < 4; i++) {
          float4 a = src[2*i], b2 = src[2*i+1];
          uint4 p;
          p.x = pack2(a.x, a.y);  p.y = pack2(a.z, a.w);
          p.z = pack2(b2.x, b2.y); p.w = pack2(b2.z, b2.w);
          ((uint4*)dstb)[i] = p;
        }
      }
    }
    __syncthreads();
    #pragma unroll
    for (int kk = 0; kk < 2; kk++) {
      bf16x8 af[4], bfr[4];
      #pragma unroll
      for (int t = 0; t < 4; t++) {
        af[t]  = *(const bf16x8*)&As[(wm + t*16 + l16) * 72 + kk*32 + quad*8];
        bfr[t] = *(const bf16x8*)&Bs[(wn + t*16 + l16) * 72 + kk*32 + quad*8];
      }
      #pragma unroll
      for (int tm = 0; tm < 4; tm++)
        #pragma unroll
        for (int tn = 0; tn < 4; tn++)
          acc[tm][tn] = __builtin_amdgcn_mfma_f32_16x16x32_bf16(af[tm], bfr[tn], acc[tm][tn], 0, 0, 0);
    }
    __syncthreads();
  }

  float bvv[4];
  #pragma unroll
  for (int tn = 0; tn < 4; tn++) bvv[tn] = bias[n0 + wn + tn*16 + l16];

  if constexpr (EPI == 0) {
    unsigned short* out = (unsigned short*)outp;
    #pragma unroll
    for (int tm = 0; tm < 4; tm++)
      #pragma unroll
      for (int tn = 0; tn < 4; tn++)
        #pragma unroll
        for (int r = 0; r < 4; r++) {
          int m = m0 + wm + tm*16 + quad*4 + r;
          int n = n0 + wn + tn*16 + l16;
          out[(size_t)m * NN_ + n] = (unsigned short)f2bf_u(acc[tm][tn][r] + bvv[tn]);
        }
  } else if constexpr (EPI == 2) {
    float* out = (float*)outp;
    #pragma unroll
    for (int tm = 0; tm < 4; tm++)
      #pragma unroll
      for (int tn = 0; tn < 4; tn++)
        #pragma unroll
        for (int r = 0; r < 4; r++) {
          int m = m0 + wm + tm*16 + quad*4 + r;
          int n = n0 + wn + tn*16 + l16;
          out[(size_t)m * NN_ + n] = acc[tm][tn][r] + bvv[tn];
        }
  } else {
    // transposed epilogue: vt[b][h][d][pos], rows contiguous in pos
    short* T = smem;                       // [128][136]
    #pragma unroll
    for (int tm = 0; tm < 4; tm++)
      #pragma unroll
      for (int tn = 0; tn < 4; tn++)
        #pragma unroll
        for (int r = 0; r < 4; r++) {
          int ml = wm + tm*16 + quad*4 + r;      // pos-local
          int nl = wn + tn*16 + l16;             // d-local
          T[nl * 136 + ml] = (short)f2bf_u(acc[tm][tn][r] + bvv[tn]);
        }
    __syncthreads();
    const int b   = m0 / L_;
    const int pos0 = m0 % L_;
    const int h   = n0 / DK_;
    const int d0  = n0 % DK_;
    unsigned short* out = (unsigned short*)outp;
    #pragma unroll
    for (int it = 0; it < 8; it++) {
      int c = tid + it * 256;                // 0..2047
      int rowd = c >> 4;                     // d-local 0..127
      int cm = (c & 15) * 8;                 // pos-local chunk
      uint4 val = *(const uint4*)&T[rowd * 136 + cm];
      *(uint4*)(out + (size_t)((b*H_ + h)*DK_ + d0 + rowd) * L_ + pos0 + cm) = val;
    }
  }
}

// -------- flash attention --------
__global__ __launch_bounds__(256)
void attn_kernel(const unsigned short* __restrict__ qp,
                 const unsigned short* __restrict__ kp,
                 const unsigned short* __restrict__ vt,
                 const int* __restrict__ mask,
                 unsigned short* __restrict__ ctx)
{
  __shared__ short plds[4][16 * 72];       // per-wave private P buffer
  const int tid  = threadIdx.x;
  const int lane = tid & 63;
  const int wave = tid >> 6;
  const int quad = lane >> 4;
  const int l16  = lane & 15;

  const int bid  = blockIdx.x;
  const int nqb  = L_ / 64;                // 32
  const int qblk = bid % nqb;
  const int bh   = bid / nqb;
  const int b    = bh / H_;
  const int h    = bh % H_;
  const int qrow0 = qblk * 64 + wave * 16;

  const float NEG_INF = -__builtin_inff();

  bf16x8 qf[8];
  {
    const unsigned short* qbase = qp + (size_t)(b*L_ + qrow0 + l16) * D_ + h*DK_ + quad*8;
    #pragma unroll
    for (int t = 0; t < 8; t++) qf[t] = *(const bf16x8*)(qbase + t*32);
  }

  f32x4 oacc[16] = {};
  float mst[4] = {NEG_INF, NEG_INF, NEG_INF, NEG_INF};
  float lst[4] = {0.f, 0.f, 0.f, 0.f};
  short* P = &plds[wave][0];

  for (int kb = 0; kb < L_ / 64; kb++) {
    const int kc0 = kb * 64;
    f32x4 s[4] = {};
    const unsigned short* kbase = kp + (size_t)(b*L_ + kc0 + l16) * D_ + h*DK_ + quad*8;
    #pragma unroll
    for (int t = 0; t < 8; t++)
      #pragma unroll
      for (int tn = 0; tn < 4; tn++) {
        bf16x8 bfm = *(const bf16x8*)(kbase + (size_t)tn*16*D_ + t*32);
        s[tn] = __builtin_amdgcn_mfma_f32_16x16x32_bf16(qf[t], bfm, s[tn], 0, 0, 0);
      }

    const int* mbase = mask + (size_t)b*L_*L_ + (size_t)(qrow0 + quad*4)*L_ + kc0 + l16;
    #pragma unroll
    for (int tn = 0; tn < 4; tn++)
      #pragma unroll
      for (int r = 0; r < 4; r++) {
        float sv = s[tn][r] * 0.0625f;          // 1/sqrt(DK)
        if (mbase[(size_t)r*L_ + tn*16]) sv = NEG_INF;
        s[tn][r] = sv;
      }

    float alpha[4];
    #pragma unroll
    for (int r = 0; r < 4; r++) {
      float rm = fmaxf(fmaxf(s[0][r], s[1][r]), fmaxf(s[2][r], s[3][r]));
      rm = fmaxf(rm, __shfl_xor(rm, 1));
      rm = fmaxf(rm, __shfl_xor(rm, 2));
      rm = fmaxf(rm, __shfl_xor(rm, 4));
      rm = fmaxf(rm, __shfl_xor(rm, 8));
      float mnew = fmaxf(mst[r], rm);
      float al = (mnew == NEG_INF) ? 1.0f : __expf(mst[r] - mnew);
      float rs = 0.f;
      #pragma unroll
      for (int tn = 0; tn < 4; tn++) {
        float sv = s[tn][r];
        float p = __expf(sv - mnew);
        if (sv == NEG_INF) p = 0.f;
        s[tn][r] = p;
        rs += p;
      }
      rs += __shfl_xor(rs, 1);
      rs += __shfl_xor(rs, 2);
      rs += __shfl_xor(rs, 4);
      rs += __shfl_xor(rs, 8);
      lst[r] = lst[r] * al + rs;
      mst[r] = mnew;
      alpha[r] = al;
    }

    #pragma unroll
    for (int dt = 0; dt < 16; dt++)
      #pragma unroll
      for (int r = 0; r < 4; r++)
        oacc[dt][r] *= alpha[r];

    #pragma unroll
    for (int tn = 0; tn < 4; tn++)
      #pragma unroll
      for (int r = 0; r < 4; r++)
        P[(quad*4 + r) * 72 + tn*16 + l16] = (short)f2bf_u(s[tn][r]);

    const unsigned short* vbase = vt + (size_t)((b*H_ + h)*DK_ + l16) * L_ + kc0 + quad*8;
    #pragma unroll
    for (int k2 = 0; k2 < 2; k2++) {
      bf16x8 ap = *(const bf16x8*)&P[l16 * 72 + k2*32 + quad*8];
      #pragma unroll
      for (int dt = 0; dt < 16; dt++) {
        bf16x8 bv = *(const bf16x8*)(vbase + (size_t)dt*16*L_ + k2*32);
        oacc[dt] = __builtin_amdgcn_mfma_f32_16x16x32_bf16(ap, bv, oacc[dt], 0, 0, 0);
      }
    }
  }

  float invl[4];
  #pragma unroll
  for (int r = 0; r < 4; r++) invl[r] = (lst[r] > 0.f) ? 1.0f / lst[r] : 0.f;
  unsigned short* obase = ctx + (size_t)(b*L_ + qrow0 + quad*4) * D_ + h*DK_ + l16;
  #pragma unroll
  for (int dt = 0; dt < 16; dt++)
    #pragma unroll
    for (int r = 0; r < 4; r++)
      obase[(size_t)r*D_ + dt*16] = (unsigned short)f2bf_u(oacc[dt][r] * invl[r]);
}

// -------- residual + layernorm --------
__global__ __launch_bounds__(256)
void ln_kernel(const float* __restrict__ fc, const float* __restrict__ resid,
               const float* __restrict__ gamma, const float* __restrict__ beta,
               float* __restrict__ out)
{
  __shared__ float sh[8];
  const int row = blockIdx.x;
  const int t = threadIdx.x;
  const int lane = t & 63, wave = t >> 6;
  float4 x = ((const float4*)(fc + (size_t)row * D_))[t];
  float4 rr = ((const float4*)(resid + (size_t)row * D_))[t];
  float4 v;
  v.x = x.x + rr.x; v.y = x.y + rr.y; v.z = x.z + rr.z; v.w = x.w + rr.w;
  float s1 = v.x + v.y + v.z + v.w;
  float s2 = v.x*v.x + v.y*v.y + v.z*v.z + v.w*v.w;
  #pragma unroll
  for (int off = 1; off < 64; off <<= 1) {
    s1 += __shfl_xor(s1, off);
    s2 += __shfl_xor(s2, off);
  }
  if (lane == 0) { sh[wave] = s1; sh[4 + wave] = s2; }
  __syncthreads();
  float t1 = sh[0] + sh[1] + sh[2] + sh[3];
  float t2 = sh[4] + sh[5] + sh[6] + sh[7];
  float mean = t1 * (1.0f / D_);
  float var = t2 * (1.0f / D_) - mean * mean;
  float rstd = rsqrtf(var + 1e-5f);
  float4 g = ((const float4*)gamma)[t];
  float4 bt = ((const float4*)beta)[t];
  float4 o;
  o.x = (v.x - mean) * rstd * g.x + bt.x;
  o.y = (v.y - mean) * rstd * g.y + bt.y;
  o.z = (v.z - mean) * rstd * g.z + bt.z;
  o.w = (v.w - mean) * rstd * g.w + bt.w;
  ((float4*)(out + (size_t)row * D_))[t] = o;
}

extern "C" void kernel_launch(void* const* d_in, const int* in_sizes, int n_in,
                              void* d_out, int out_size, void* d_ws, size_t ws_size,
                              hipStream_t stream)
{
  const float* q   = (const float*)d_in[0];
  const float* k   = (const float*)d_in[1];
  const float* v   = (const float*)d_in[2];
  const int* mask  = (const int*)d_in[3];
  const float* Wq  = (const float*)d_in[4];
  const float* bq  = (const float*)d_in[5];
  const float* Wk  = (const float*)d_in[6];
  const float* bk  = (const float*)d_in[7];
  const float* Wv  = (const float*)d_in[8];
  const float* bv  = (const float*)d_in[9];
  const float* Wfc = (const float*)d_in[10];
  const float* bfc = (const float*)d_in[11];
  const float* gamma = (const float*)d_in[12];
  const float* beta  = (const float*)d_in[13];

  const size_t NE = (size_t)MM_ * D_;            // 16M elements
  char* ws = (char*)d_ws;
  unsigned short* qp  = (unsigned short*)ws;      // 32MB
  unsigned short* kp  = qp + NE;                  // 32MB
  unsigned short* vt  = kp + NE;                  // 32MB
  unsigned short* ctx = vt + NE;                  // 32MB

  const size_t SLOW_NEED = 128ull * 1024 * 1024;
  const size_t FAST_NEED = 232ull * 1024 * 1024;
  if (ws_size < SLOW_NEED) return;               // clean-fail signal (absmax = 5.406)

  dim3 gg(NN_ / 128, MM_ / 128);                 // (8, 128)
  const int attn_grid = B_ * H_ * (L_ / 64);     // 1024

  if (ws_size >= FAST_NEED) {
    unsigned short* Xq  = ctx + NE;               // 32MB
    unsigned short* Xk  = Xq + NE;
    unsigned short* Xv  = Xk + NE;
    unsigned short* Wqb = Xv + NE;                // 2MB each
    unsigned short* Wkb = Wqb + (size_t)D_ * D_;
    unsigned short* Wvb = Wkb + (size_t)D_ * D_;
    unsigned short* Wfb = Wvb + (size_t)D_ * D_;
    float* fc = (float*)Xq;                       // reuse Xq+Xk after attention (64MB)

    cvt_kernel<<<4096, 256, 0, stream>>>(q, Xq, (int)(NE / 4));
    cvt_kernel<<<4096, 256, 0, stream>>>(k, Xk, (int)(NE / 4));
    cvt_kernel<<<4096, 256, 0, stream>>>(v, Xv, (int)(NE / 4));
    cvt_kernel<<<1024, 256, 0, stream>>>(Wq, Wqb, D_ * D_ / 4);
    cvt_kernel<<<1024, 256, 0, stream>>>(Wk, Wkb, D_ * D_ / 4);
    cvt_kernel<<<1024, 256, 0, stream>>>(Wv, Wvb, D_ * D_ / 4);
    cvt_kernel<<<1024, 256, 0, stream>>>(Wfc, Wfb, D_ * D_ / 4);

    gemm_kernel<1, 1, 0><<<gg, 256, 0, stream>>>(Xq, Wqb, bq, qp);
    gemm_kernel<1, 1, 0><<<gg, 256, 0, stream>>>(Xk, Wkb, bk, kp);
    gemm_kernel<1, 1, 1><<<gg, 256, 0, stream>>>(Xv, Wvb, bv, vt);
    attn_kernel<<<attn_grid, 256, 0, stream>>>(qp, kp, vt, mask, ctx);
    gemm_kernel<1, 1, 2><<<gg, 256, 0, stream>>>(ctx, Wfb, bfc, fc);
    ln_kernel<<<MM_, 256, 0, stream>>>(fc, q, gamma, beta, (float*)d_out);
  } else {
    float* fc = (float*)ws;                       // reuse qp+kp after attention (64MB)
    gemm_kernel<0, 0, 0><<<gg, 256, 0, stream>>>(q, Wq, bq, qp);
    gemm_kernel<0, 0, 0><<<gg, 256, 0, stream>>>(k, Wk, bk, kp);
    gemm_kernel<0, 0, 1><<<gg, 256, 0, stream>>>(v, Wv, bv, vt);
    attn_kernel<<<attn_grid, 256, 0, stream>>>(qp, kp, vt, mask, ctx);
    gemm_kernel<1, 0, 2><<<gg, 256, 0, stream>>>(ctx, Wfc, bfc, fc);
    ln_kernel<<<MM_, 256, 0, stream>>>(fc, q, gamma, beta, (float*)d_out);
  }
}

// Round 4
// 1037.367 us; speedup vs baseline: 2.0785x; 2.0785x over previous
//
#include <hip/hip_runtime.h>
#include <stdint.h>

#define B_ 8
#define L_ 2048
#define D_ 1024
#define H_ 4
#define DK_ 256
#define MM_ (B_*L_)   // 16384
#define KK_ D_        // 1024
#define NN_ D_        // 1024
#define KBLK 32

typedef __bf16 bf16x8 __attribute__((ext_vector_type(8)));
typedef float  f32x4  __attribute__((ext_vector_type(4)));

__device__ __forceinline__ uint32_t f2bf_u(float f) {
  union { float f; uint32_t u; } v; v.f = f;
  return (v.u + 0x7FFFu + ((v.u >> 16) & 1u)) >> 16;
}
__device__ __forceinline__ uint32_t pack2(float x, float y) {
  return f2bf_u(x) | (f2bf_u(y) << 16);
}

// -------- fp32 -> bf16 convert (fast path only) --------
__global__ __launch_bounds__(256) void cvt_kernel(const float* __restrict__ src,
                                                  unsigned short* __restrict__ dst, int n4) {
  int i = blockIdx.x * blockDim.x + threadIdx.x;
  int stride = gridDim.x * blockDim.x;
  for (; i < n4; i += stride) {
    float4 f = ((const float4*)src)[i];
    uint2 u; u.x = pack2(f.x, f.y); u.y = pack2(f.z, f.w);
    ((uint2*)dst)[i] = u;
  }
}

// -------- GEMM: out[m,n] = sum_k A[m,k]*W[n,k] + bias[n] --------
// ABF/WBF: operand is bf16 (1) or fp32 (0).  EPI: 0=bf16 row-major, 1=bf16 transposed vt, 2=fp32
template<int ABF, int WBF, int EPI>
__global__ __launch_bounds__(256)
void gemm_kernel(const void* __restrict__ Ap, const void* __restrict__ Wp,
                 const float* __restrict__ bias, void* __restrict__ outp)
{
  __shared__ short smem[18432];          // A: [128][72], B: [128][72]; reused for transpose
  short* As = smem;
  short* Bs = smem + 9216;

  const int tid  = threadIdx.x;
  const int lane = tid & 63;
  const int wave = tid >> 6;
  const int quad = lane >> 4;
  const int l16  = lane & 15;
  const int wm = (wave >> 1) * 64;
  const int wn = (wave & 1) * 64;
  const int m0 = blockIdx.y * 128;
  const int n0 = blockIdx.x * 128;

  const int srow = tid >> 1;             // 0..127
  const int scol = (tid & 1) * 32;       // 0 or 32

  f32x4 acc[4][4] = {};

  for (int ks = 0; ks < KK_ / 64; ks++) {
    const int k0 = ks * 64;
    {
      short* dst = &As[srow * 72 + scol];
      if constexpr (ABF) {
        const uint4* src = (const uint4*)((const unsigned short*)Ap + (size_t)(m0 + srow) * KK_ + k0 + scol);
        #pragma unroll
        for (int i = 0; i < 4; i++) ((uint4*)dst)[i] = src[i];
      } else {
        const float4* src = (const float4*)((const float*)Ap + (size_t)(m0 + srow) * KK_ + k0 + scol);
        #pragma unroll
        for (int i = 0; i < 4; i++) {
          float4 a = src[2*i], b2 = src[2*i+1];
          uint4 p;
          p.x = pack2(a.x, a.y);  p.y = pack2(a.z, a.w);
          p.z = pack2(b2.x, b2.y); p.w = pack2(b2.z, b2.w);
          ((uint4*)dst)[i] = p;
        }
      }
      short* dstb = &Bs[srow * 72 + scol];
      if constexpr (WBF) {
        const uint4* src = (const uint4*)((const unsigned short*)Wp + (size_t)(n0 + srow) * KK_ + k0 + scol);
        #pragma unroll
        for (int i = 0; i < 4; i++) ((uint4*)dstb)[i] = src[i];
      } else {
        const float4* src = (const float4*)((const float*)Wp + (size_t)(n0 + srow) * KK_ + k0 + scol);
        #pragma unroll
        for (int i = 0; i < 4; i++) {
          float4 a = src[2*i], b2 = src[2*i+1];
          uint4 p;
          p.x = pack2(a.x, a.y);  p.y = pack2(a.z, a.w);
          p.z = pack2(b2.x, b2.y); p.w = pack2(b2.z, b2.w);
          ((uint4*)dstb)[i] = p;
        }
      }
    }
    __syncthreads();
    #pragma unroll
    for (int kk = 0; kk < 2; kk++) {
      bf16x8 af[4], bfr[4];
      #pragma unroll
      for (int t = 0; t < 4; t++) {
        af[t]  = *(const bf16x8*)&As[(wm + t*16 + l16) * 72 + kk*32 + quad*8];
        bfr[t] = *(const bf16x8*)&Bs[(wn + t*16 + l16) * 72 + kk*32 + quad*8];
      }
      #pragma unroll
      for (int tm = 0; tm < 4; tm++)
        #pragma unroll
        for (int tn = 0; tn < 4; tn++)
          acc[tm][tn] = __builtin_amdgcn_mfma_f32_16x16x32_bf16(af[tm], bfr[tn], acc[tm][tn], 0, 0, 0);
    }
    __syncthreads();
  }

  float bvv[4];
  #pragma unroll
  for (int tn = 0; tn < 4; tn++) bvv[tn] = bias[n0 + wn + tn*16 + l16];

  if constexpr (EPI == 0) {
    unsigned short* out = (unsigned short*)outp;
    #pragma unroll
    for (int tm = 0; tm < 4; tm++)
      #pragma unroll
      for (int tn = 0; tn < 4; tn++)
        #pragma unroll
        for (int r = 0; r < 4; r++) {
          int m = m0 + wm + tm*16 + quad*4 + r;
          int n = n0 + wn + tn*16 + l16;
          out[(size_t)m * NN_ + n] = (unsigned short)f2bf_u(acc[tm][tn][r] + bvv[tn]);
        }
  } else if constexpr (EPI == 2) {
    float* out = (float*)outp;
    #pragma unroll
    for (int tm = 0; tm < 4; tm++)
      #pragma unroll
      for (int tn = 0; tn < 4; tn++)
        #pragma unroll
        for (int r = 0; r < 4; r++) {
          int m = m0 + wm + tm*16 + quad*4 + r;
          int n = n0 + wn + tn*16 + l16;
          out[(size_t)m * NN_ + n] = acc[tm][tn][r] + bvv[tn];
        }
  } else {
    // transposed epilogue: vt[b][h][d][pos], rows contiguous in pos
    short* T = smem;                       // [128][136]
    #pragma unroll
    for (int tm = 0; tm < 4; tm++)
      #pragma unroll
      for (int tn = 0; tn < 4; tn++)
        #pragma unroll
        for (int r = 0; r < 4; r++) {
          int ml = wm + tm*16 + quad*4 + r;      // pos-local
          int nl = wn + tn*16 + l16;             // d-local
          T[nl * 136 + ml] = (short)f2bf_u(acc[tm][tn][r] + bvv[tn]);
        }
    __syncthreads();
    const int b   = m0 / L_;
    const int pos0 = m0 % L_;
    const int h   = n0 / DK_;
    const int d0  = n0 % DK_;
    unsigned short* out = (unsigned short*)outp;
    #pragma unroll
    for (int it = 0; it < 8; it++) {
      int c = tid + it * 256;                // 0..2047
      int rowd = c >> 4;                     // d-local 0..127
      int cm = (c & 15) * 8;                 // pos-local chunk
      uint4 val = *(const uint4*)&T[rowd * 136 + cm];
      *(uint4*)(out + (size_t)((b*H_ + h)*DK_ + d0 + rowd) * L_ + pos0 + cm) = val;
    }
  }
}

// -------- flash attention (LDS-staged K/V tiles, 32-kpos blocks, 42.5KB LDS) --------
__global__ __launch_bounds__(256)
void attn_kernel(const unsigned short* __restrict__ qp,
                 const unsigned short* __restrict__ kp,
                 const unsigned short* __restrict__ vt,
                 const int* __restrict__ mask,
                 unsigned short* __restrict__ ctx)
{
  __shared__ short Ks[KBLK * 264];         // K-tile [kpos][d], stride 264
  __shared__ short Vs[256 * 40];           // V-tile [d][kpos], stride 40
  __shared__ short plds[4][16 * 40];       // per-wave private P buffer

  const int tid  = threadIdx.x;
  const int lane = tid & 63;
  const int wave = tid >> 6;
  const int quad = lane >> 4;
  const int l16  = lane & 15;

  const int bid  = blockIdx.x;
  const int nqb  = L_ / 64;                // 32
  const int qblk = bid % nqb;
  const int bh   = bid / nqb;
  const int b    = bh / H_;
  const int h    = bh % H_;
  const int qrow0 = qblk * 64 + wave * 16;

  const float NEG_INF = -__builtin_inff();

  bf16x8 qf[8];
  {
    const unsigned short* qbase = qp + (size_t)(b*L_ + qrow0 + l16) * D_ + h*DK_ + quad*8;
    #pragma unroll
    for (int t = 0; t < 8; t++) qf[t] = *(const bf16x8*)(qbase + t*32);
  }

  f32x4 oacc[16] = {};
  float mst[4] = {NEG_INF, NEG_INF, NEG_INF, NEG_INF};
  float lst[4] = {0.f, 0.f, 0.f, 0.f};
  short* P = &plds[wave][0];

  // staging maps (constant across iterations)
  const int krow  = tid >> 3;              // 0..31
  const int kcol8 = tid & 7;               // chunk id within row
  const int vd    = tid >> 2;              // 0..63 (+it*64)
  const int vcol  = (tid & 3) * 8;         // shorts

  for (int kb = 0; kb < L_ / KBLK; kb++) {
    const int kc0 = kb * KBLK;

    // ---- stage K-tile: 32 rows x 256 shorts ----
    {
      const unsigned short* srow = kp + (size_t)(b*L_ + kc0 + krow) * D_ + h*DK_;
      #pragma unroll
      for (int i = 0; i < 4; i++) {
        int c = (kcol8 + i*8) * 8;
        *(uint4*)&Ks[krow * 264 + c] = *(const uint4*)(srow + c);
      }
    }
    // ---- stage V-tile: 256 rows x 32 shorts ----
    {
      #pragma unroll
      for (int it = 0; it < 4; it++) {
        int d = it * 64 + vd;
        *(uint4*)&Vs[d * 40 + vcol] =
          *(const uint4*)(vt + (size_t)((b*H_ + h)*DK_ + d) * L_ + kc0 + vcol);
      }
    }
    __syncthreads();

    // ---- QK^T from LDS ----
    f32x4 s[2] = {};
    #pragma unroll
    for (int t = 0; t < 8; t++)
      #pragma unroll
      for (int tn = 0; tn < 2; tn++) {
        bf16x8 bfm = *(const bf16x8*)&Ks[(tn*16 + l16) * 264 + t*32 + quad*8];
        s[tn] = __builtin_amdgcn_mfma_f32_16x16x32_bf16(qf[t], bfm, s[tn], 0, 0, 0);
      }

    const int* mbase = mask + (size_t)b*L_*L_ + (size_t)(qrow0 + quad*4)*L_ + kc0 + l16;
    #pragma unroll
    for (int tn = 0; tn < 2; tn++)
      #pragma unroll
      for (int r = 0; r < 4; r++) {
        float sv = s[tn][r] * 0.0625f;          // 1/sqrt(DK)
        if (mbase[(size_t)r*L_ + tn*16]) sv = NEG_INF;
        s[tn][r] = sv;
      }

    float alpha[4];
    #pragma unroll
    for (int r = 0; r < 4; r++) {
      float rm = fmaxf(s[0][r], s[1][r]);
      rm = fmaxf(rm, __shfl_xor(rm, 1));
      rm = fmaxf(rm, __shfl_xor(rm, 2));
      rm = fmaxf(rm, __shfl_xor(rm, 4));
      rm = fmaxf(rm, __shfl_xor(rm, 8));
      float mnew = fmaxf(mst[r], rm);
      float al = (mnew == NEG_INF) ? 1.0f : __expf(mst[r] - mnew);
      float rs = 0.f;
      #pragma unroll
      for (int tn = 0; tn < 2; tn++) {
        float sv = s[tn][r];
        float p = __expf(sv - mnew);
        if (sv == NEG_INF) p = 0.f;
        s[tn][r] = p;
        rs += p;
      }
      rs += __shfl_xor(rs, 1);
      rs += __shfl_xor(rs, 2);
      rs += __shfl_xor(rs, 4);
      rs += __shfl_xor(rs, 8);
      lst[r] = lst[r] * al + rs;
      mst[r] = mnew;
      alpha[r] = al;
    }

    #pragma unroll
    for (int dt = 0; dt < 16; dt++)
      #pragma unroll
      for (int r = 0; r < 4; r++)
        oacc[dt][r] *= alpha[r];

    #pragma unroll
    for (int tn = 0; tn < 2; tn++)
      #pragma unroll
      for (int r = 0; r < 4; r++)
        P[(quad*4 + r) * 40 + tn*16 + l16] = (short)f2bf_u(s[tn][r]);

    // ---- PV from LDS ----
    {
      bf16x8 ap = *(const bf16x8*)&P[l16 * 40 + quad*8];
      #pragma unroll
      for (int dt = 0; dt < 16; dt++) {
        bf16x8 bv = *(const bf16x8*)&Vs[(dt*16 + l16) * 40 + quad*8];
        oacc[dt] = __builtin_amdgcn_mfma_f32_16x16x32_bf16(ap, bv, oacc[dt], 0, 0, 0);
      }
    }
    __syncthreads();
  }

  float invl[4];
  #pragma unroll
  for (int r = 0; r < 4; r++) invl[r] = (lst[r] > 0.f) ? 1.0f / lst[r] : 0.f;
  unsigned short* obase = ctx + (size_t)(b*L_ + qrow0 + quad*4) * D_ + h*DK_ + l16;
  #pragma unroll
  for (int dt = 0; dt < 16; dt++)
    #pragma unroll
    for (int r = 0; r < 4; r++)
      obase[(size_t)r*D_ + dt*16] = (unsigned short)f2bf_u(oacc[dt][r] * invl[r]);
}

// -------- residual + layernorm --------
__global__ __launch_bounds__(256)
void ln_kernel(const float* __restrict__ fc, const float* __restrict__ resid,
               const float* __restrict__ gamma, const float* __restrict__ beta,
               float* __restrict__ out)
{
  __shared__ float sh[8];
  const int row = blockIdx.x;
  const int t = threadIdx.x;
  const int lane = t & 63, wave = t >> 6;
  float4 x = ((const float4*)(fc + (size_t)row * D_))[t];
  float4 rr = ((const float4*)(resid + (size_t)row * D_))[t];
  float4 v;
  v.x = x.x + rr.x; v.y = x.y + rr.y; v.z = x.z + rr.z; v.w = x.w + rr.w;
  float s1 = v.x + v.y + v.z + v.w;
  float s2 = v.x*v.x + v.y*v.y + v.z*v.z + v.w*v.w;
  #pragma unroll
  for (int off = 1; off < 64; off <<= 1) {
    s1 += __shfl_xor(s1, off);
    s2 += __shfl_xor(s2, off);
  }
  if (lane == 0) { sh[wave] = s1; sh[4 + wave] = s2; }
  __syncthreads();
  float t1 = sh[0] + sh[1] + sh[2] + sh[3];
  float t2 = sh[4] + sh[5] + sh[6] + sh[7];
  float mean = t1 * (1.0f / D_);
  float var = t2 * (1.0f / D_) - mean * mean;
  float rstd = rsqrtf(var + 1e-5f);
  float4 g = ((const float4*)gamma)[t];
  float4 bt = ((const float4*)beta)[t];
  float4 o;
  o.x = (v.x - mean) * rstd * g.x + bt.x;
  o.y = (v.y - mean) * rstd * g.y + bt.y;
  o.z = (v.z - mean) * rstd * g.z + bt.z;
  o.w = (v.w - mean) * rstd * g.w + bt.w;
  ((float4*)(out + (size_t)row * D_))[t] = o;
}

extern "C" void kernel_launch(void* const* d_in, const int* in_sizes, int n_in,
                              void* d_out, int out_size, void* d_ws, size_t ws_size,
                              hipStream_t stream)
{
  const float* q   = (const float*)d_in[0];
  const float* k   = (const float*)d_in[1];
  const float* v   = (const float*)d_in[2];
  const int* mask  = (const int*)d_in[3];
  const float* Wq  = (const float*)d_in[4];
  const float* bq  = (const float*)d_in[5];
  const float* Wk  = (const float*)d_in[6];
  const float* bk  = (const float*)d_in[7];
  const float* Wv  = (const float*)d_in[8];
  const float* bv  = (const float*)d_in[9];
  const float* Wfc = (const float*)d_in[10];
  const float* bfc = (const float*)d_in[11];
  const float* gamma = (const float*)d_in[12];
  const float* beta  = (const float*)d_in[13];

  const size_t NE = (size_t)MM_ * D_;            // 16M elements
  char* ws = (char*)d_ws;
  unsigned short* qp  = (unsigned short*)ws;      // 32MB
  unsigned short* kp  = qp + NE;                  // 32MB
  unsigned short* vt  = kp + NE;                  // 32MB
  unsigned short* ctx = vt + NE;                  // 32MB

  const size_t SLOW_NEED = 128ull * 1024 * 1024;
  const size_t FAST_NEED = 232ull * 1024 * 1024;
  if (ws_size < SLOW_NEED) return;               // clean-fail signal (absmax = 5.406)

  dim3 gg(NN_ / 128, MM_ / 128);                 // (8, 128)
  const int attn_grid = B_ * H_ * (L_ / 64);     // 1024

  if (ws_size >= FAST_NEED) {
    unsigned short* Xq  = ctx + NE;               // 32MB
    unsigned short* Xk  = Xq + NE;
    unsigned short* Xv  = Xk + NE;
    unsigned short* Wqb = Xv + NE;                // 2MB each
    unsigned short* Wkb = Wqb + (size_t)D_ * D_;
    unsigned short* Wvb = Wkb + (size_t)D_ * D_;
    unsigned short* Wfb = Wvb + (size_t)D_ * D_;
    float* fc = (float*)Xq;                       // reuse Xq+Xk after attention (64MB)

    cvt_kernel<<<4096, 256, 0, stream>>>(q, Xq, (int)(NE / 4));
    cvt_kernel<<<4096, 256, 0, stream>>>(k, Xk, (int)(NE / 4));
    cvt_kernel<<<4096, 256, 0, stream>>>(v, Xv, (int)(NE / 4));
    cvt_kernel<<<1024, 256, 0, stream>>>(Wq, Wqb, D_ * D_ / 4);
    cvt_kernel<<<1024, 256, 0, stream>>>(Wk, Wkb, D_ * D_ / 4);
    cvt_kernel<<<1024, 256, 0, stream>>>(Wv, Wvb, D_ * D_ / 4);
    cvt_kernel<<<1024, 256, 0, stream>>>(Wfc, Wfb, D_ * D_ / 4);

    gemm_kernel<1, 1, 0><<<gg, 256, 0, stream>>>(Xq, Wqb, bq, qp);
    gemm_kernel<1, 1, 0><<<gg, 256, 0, stream>>>(Xk, Wkb, bk, kp);
    gemm_kernel<1, 1, 1><<<gg, 256, 0, stream>>>(Xv, Wvb, bv, vt);
    attn_kernel<<<attn_grid, 256, 0, stream>>>(qp, kp, vt, mask, ctx);
    gemm_kernel<1, 1, 2><<<gg, 256, 0, stream>>>(ctx, Wfb, bfc, fc);
    ln_kernel<<<MM_, 256, 0, stream>>>(fc, q, gamma, beta, (float*)d_out);
  } else {
    float* fc = (float*)ws;                       // reuse qp+kp after attention (64MB)
    gemm_kernel<0, 0, 0><<<gg, 256, 0, stream>>>(q, Wq, bq, qp);
    gemm_kernel<0, 0, 0><<<gg, 256, 0, stream>>>(k, Wk, bk, kp);
    gemm_kernel<0, 0, 1><<<gg, 256, 0, stream>>>(v, Wv, bv, vt);
    attn_kernel<<<attn_grid, 256, 0, stream>>>(qp, kp, vt, mask, ctx);
    gemm_kernel<1, 0, 2><<<gg, 256, 0, stream>>>(ctx, Wfc, bfc, fc);
    ln_kernel<<<MM_, 256, 0, stream>>>(fc, q, gamma, beta, (float*)d_out);
  }
}